// Round 13
// baseline (390.236 us; speedup 1.0000x reference)
//
#include <hip/hip_runtime.h>

// Problem constants (from reference)
#define NB      128
#define ND      8
#define NK      8
#define TLEN    512
#define NSTEPS  496

#define INVLN2f 1.44269504088896340736f

__device__ __forceinline__ float fexp(float x) { return __expf(x); }
__device__ __forceinline__ float flog(float x) { return __logf(x); }
__device__ __forceinline__ float frcp(float x) { return __builtin_amdgcn_rcpf(x); }
__device__ __forceinline__ float elur(float x) { return x > 0.f ? x : fexp(x) - 1.f; }

#if defined(__has_builtin)
#if __has_builtin(__builtin_amdgcn_exp2f)
#define fexp2(x) __builtin_amdgcn_exp2f(x)
#endif
#endif
#ifndef fexp2
#define fexp2(x) exp2f(x)
#endif

// DPP helpers (quad_perm broadcasts + row rotates)
#define DPP_QP0(v)  __int_as_float(__builtin_amdgcn_mov_dpp(__float_as_int(v), 0x00, 0xF, 0xF, false))
#define DPP_QP1(v)  __int_as_float(__builtin_amdgcn_mov_dpp(__float_as_int(v), 0x55, 0xF, 0xF, false))
#define DPP_QP2(v)  __int_as_float(__builtin_amdgcn_mov_dpp(__float_as_int(v), 0xAA, 0xF, 0xF, false))
#define DPP_QP3(v)  __int_as_float(__builtin_amdgcn_mov_dpp(__float_as_int(v), 0xFF, 0xF, 0xF, false))
#define DPP_ROR4(v) __int_as_float(__builtin_amdgcn_mov_dpp(__float_as_int(v), 0x124, 0xF, 0xF, false))
#define DPP_X1(v)   __int_as_float(__builtin_amdgcn_mov_dpp(__float_as_int(v), 0xB1, 0xF, 0xF, false))
#define DPP_X2(v)   __int_as_float(__builtin_amdgcn_mov_dpp(__float_as_int(v), 0x4E, 0xF, 0xF, false))
#define DPP_RORN(v, ctrl) __int_as_float(__builtin_amdgcn_mov_dpp(__float_as_int(v), (ctrl), 0xF, 0xF, false))

#define RED8_MAX(m) { m = fmaxf(m, DPP_X1(m)); m = fmaxf(m, DPP_X2(m)); m = fmaxf(m, DPP_ROR4(m)); }
#define RED8_SUM(s) { s = s + DPP_X1(s); s = s + DPP_X2(s); s = s + DPP_ROR4(s); }

#if defined(__has_builtin)
#if __has_builtin(__builtin_amdgcn_permlane32_swap)
#define HAVE_PLSWAP32 1
#endif
#if __has_builtin(__builtin_amdgcn_permlane16_swap)
#define HAVE_PLSWAP16 1
#endif
#endif

typedef unsigned int uint2v __attribute__((ext_vector_type(2)));

#ifdef HAVE_PLSWAP32
__device__ __forceinline__ float xhalfsum(float v) {   // v + v[lane^32], VALU
    unsigned int u = __float_as_uint(v);
    uint2v r = __builtin_amdgcn_permlane32_swap(u, u, false, false);
    return __uint_as_float(r[0]) + __uint_as_float(r[1]);
}
#else
__device__ __forceinline__ float xhalfsum(float v) { return v + __shfl_xor(v, 32); }
#endif

// row-swapped value (lane^16): probe-selected element of permlane16_swap pair
#ifdef HAVE_PLSWAP16
#define PLSWAP16(dst, v) { \
    unsigned int _u = __float_as_uint(v); \
    uint2v _pr = __builtin_amdgcn_permlane16_swap(_u, _u, false, false); \
    dst = __uint_as_float(sel16 ? _pr[0] : _pr[1]); }
#else
#define PLSWAP16(dst, v) { dst = __shfl_xor((v), 16); }
#endif

// one rotation term: value from lane (base-rotated by r), dual-tap FMA
#define ROTF(r, na, oa, WN, WO) { \
    float _v = DPP_RORN(_bs, 0x120 + (r)); \
    na = fmaf(WN[r], _v, na); \
    oa = fmaf(WO[r], _v, oa); }

// all-VALU 16-channel gather + dual 16-term dot (no LDS!)
// ov: own activation (channel lane&31, exact ^32 replication).
// Weights pre-rotated per lane: W[r] = w[((lane&15) + dir*r)&15 + 16*(lane>>5)].
#define GATHER_DOT(ov, WN, WO, nres, ores)                                        \
  {                                                                               \
    float _swp;                                                                   \
    PLSWAP16(_swp, ov);                                                           \
    float _bs = useown ? (ov) : _swp;                                             \
    float _n0 = WN[0] * _bs, _oA = WO[0] * _bs;                                   \
    float _n1 = 0.f, _oB = 0.f, _n2 = 0.f, _oC = 0.f, _n3 = 0.f, _oD = 0.f;       \
    ROTF(1,  _n1, _oB, WN, WO) ROTF(2,  _n2, _oC, WN, WO)                         \
    ROTF(3,  _n3, _oD, WN, WO) ROTF(4,  _n0, _oA, WN, WO)                         \
    ROTF(5,  _n1, _oB, WN, WO) ROTF(6,  _n2, _oC, WN, WO)                         \
    ROTF(7,  _n3, _oD, WN, WO) ROTF(8,  _n0, _oA, WN, WO)                         \
    ROTF(9,  _n1, _oB, WN, WO) ROTF(10, _n2, _oC, WN, WO)                         \
    ROTF(11, _n3, _oD, WN, WO) ROTF(12, _n0, _oA, WN, WO)                         \
    ROTF(13, _n1, _oB, WN, WO) ROTF(14, _n2, _oC, WN, WO)                         \
    ROTF(15, _n3, _oD, WN, WO)                                                    \
    nres = (_n0 + _n1) + (_n2 + _n3);                                             \
    ores = (_oA + _oB) + (_oC + _oD);                                             \
  }

// One scan step. ZP = F(q-2) slots (overwritten with F(q)), RP its 1/sum;
// ZC = F(q-1), RC its 1/sum (y = F*R). Slot k holds channel k^4p.
// ZQ2 at tail == wzo.y(q-1). gls holds g2 = g*tinv/ln2.
#define STEP(qv, S1, S2, S3, ZP, ZC, RP, RC, DO_OUT)                              \
  {                                                                               \
    const int q_ = (qv);                                                          \
    float g2_own = 0.f;                                                           \
    if (DO_OUT) g2_own = gls[(q_ - 15) * NK + o3];                                \
    const float4* _xq = (const float4*)&xcol[q_ + tap][0];                        \
    float4 _xa = _xq[0], _xb = _xq[1];                                            \
    /* layer 0 */                                                                 \
    float _z0 = fmaf(wzn[0], ZC[0], 0.f);                                         \
    float _z1 = fmaf(wzn[1], ZC[1], 0.f);                                         \
    float _z2 = fmaf(wzn[2], ZC[2], 0.f);                                         \
    float _z3 = fmaf(wzn[3], ZC[3], 0.f);                                         \
    _z0 = fmaf(wzn[4], ZC[4], _z0);                                               \
    _z1 = fmaf(wzn[5], ZC[5], _z1);                                               \
    _z2 = fmaf(wzn[6], ZC[6], _z2);                                               \
    _z3 = fmaf(wzn[7], ZC[7], _z3);                                               \
    float o0v = elur(fmaf((_z0 + _z1) + (_z2 + _z3), RC, XZ));                    \
    /* layer 1 (all-VALU gather) */                                               \
    float n1, d1o;                                                                \
    GATHER_DOT(o0v, w1n, w1o, n1, d1o);                                           \
    float o1v = elur(xhalfsum(n1) + P1[S1]);                                      \
    P1[S1] = b1r + xhalfsum(d1o);                                                 \
    /* layer 2 */                                                                 \
    float n2, d2o;                                                                \
    GATHER_DOT(o1v, w2n, w2o, n2, d2o);                                           \
    float o2v = elur(xhalfsum(n2) + P2[S2]);                                      \
    P2[S2] = b2r + xhalfsum(d2o);                                                 \
    /* layer 3 */                                                                 \
    float n3, d3o;                                                                \
    GATHER_DOT(o2v, w3n, w3o, n3, d3o);                                           \
    float a3m = elur(xhalfsum(n3) + P3[S3]);                                      \
    P3[S3] = b3r + xhalfsum(d3o);                                                 \
    if (DO_OUT) {                                                                 \
      /* feedback gumbel-softmax: single exp2, no max-sub */                      \
      float F = fexp2(fmaf(a3m, klog, g2_own));                                   \
      float S = F; RED8_SUM(S);                                                   \
      float r2 = frcp(S);                                                         \
      RP = r2;                                                                    \
      float _t = DPP_ROR4(F);                                                     \
      ZP[0] = DPP_QP0(F);  ZP[1] = DPP_QP1(F);  ZP[2] = DPP_QP2(F);               \
      ZP[3] = DPP_QP3(F);                                                         \
      ZP[4] = DPP_QP0(_t); ZP[5] = DPP_QP1(_t); ZP[6] = DPP_QP2(_t);              \
      ZP[7] = DPP_QP3(_t);                                                        \
      /* off-path: old-tap z-dot wzo.y(q_) — consumed at step q_+2 */             \
      {                                                                           \
        float z0 = fmaf(wzo[0], ZP[0], fmaf(wzo[1], ZP[1], 0.f));                 \
        float z1 = fmaf(wzo[2], ZP[2], fmaf(wzo[3], ZP[3], 0.f));                 \
        float z2 = fmaf(wzo[4], ZP[4], fmaf(wzo[5], ZP[5], 0.f));                 \
        float z3 = fmaf(wzo[6], ZP[6], fmaf(wzo[7], ZP[7], 0.f));                 \
        ZQ2n = ((z0 + z1) + (z2 + z3)) * r2;                                      \
      }                                                                           \
      /* off-path: log-softmax output */                                          \
      float mx = a3m; RED8_MAX(mx);                                               \
      float e = fexp(a3m - mx);                                                   \
      float se = e; RED8_SUM(se);                                                 \
      float lse = mx + flog(se);                                                  \
      if (lane < 8) {                                                             \
        outg[zoff + lane * TLEN + q_ + 1]       = F * r2;                         \
        outg[qoff + lane * NSTEPS + (q_ - 15)]  = a3m - lse;                      \
      }                                                                           \
    }                                                                             \
    /* park x-part + old-z for step q_+1 */                                       \
    {                                                                             \
      float s0 = fmaf(wxr[0], _xa.x, fmaf(wxr[1], _xa.y, 0.f));                   \
      float s1 = fmaf(wxr[2], _xa.z, fmaf(wxr[3], _xa.w, 0.f));                   \
      float s2 = fmaf(wxr[4], _xb.x, fmaf(wxr[5], _xb.y, 0.f));                   \
      float s3 = fmaf(wxr[6], _xb.z, fmaf(wxr[7], _xb.w, 0.f));                   \
      float xp = (s0 + s1) + (s2 + s3);                                           \
      XZ = xhalfsum(xp) + b0r + ZQ2;                                              \
      ZQ2 = ZQ2n;                                                                 \
    }                                                                             \
  }

__global__ __launch_bounds__(64, 1)
void regime_scan_kernel(const float* __restrict__ xg,
                        const float* __restrict__ tempg,
                        const float* __restrict__ ug,
                        const float* __restrict__ w0g,
                        const float* __restrict__ b0g,
                        const float* __restrict__ w1g,
                        const float* __restrict__ b1g,
                        const float* __restrict__ w2g,
                        const float* __restrict__ b2g,
                        const float* __restrict__ w3g,
                        const float* __restrict__ b3g,
                        float* __restrict__ outg)
{
    __shared__ __align__(16) float xcol[527][8];     // 16.9 KB
    __shared__ __align__(16) float gls[NSTEPS * NK]; // 15.9 KB (holds g2)

    const int lane = threadIdx.x;
    const int b    = blockIdx.x;
    const int c    = lane & 31;            // channel owned
    const int o3   = lane & 7;             // layer-3 channel owned
    const int l15  = lane & 15;
    const int hbase = (lane >> 5) << 4;    // K-half base (0 or 16)
    const int tap  = (lane < 32) ? 1 : 0;  // x-park tap role
    const int p4   = (lane & 4);           // slot-order parity*4
    const int myrow = lane >> 4;
    const bool useown = (myrow == 0) || (myrow == 3);

    // ---- runtime probes (uniform): ror direction, permlane16_swap pair index --
    int dir;
    {
        int rr1 = __builtin_amdgcn_mov_dpp(l15, 0x121, 0xF, 0xF, false); // row_ror:1
        dir = (rr1 == ((l15 + 1) & 15)) ? 1 : -1;
    }
    bool sel16 = false;
#ifdef HAVE_PLSWAP16
    {
        uint2v pr = __builtin_amdgcn_permlane16_swap((unsigned)lane, (unsigned)lane, false, false);
        sel16 = (pr[0] == (unsigned)(lane ^ 16));
    }
#endif

    // ---- per-lane weights ----
    float wzn[8], wzo[8];                  // layer0 z weights, slot order
    #pragma unroll
    for (int k = 0; k < 8; ++k) {
        int ch = k ^ p4;
        wzn[k] = w0g[c * 32 + (8 + ch) * 2 + 1];
        wzo[k] = w0g[c * 32 + (8 + ch) * 2 + 0];
    }
    float wxr[8];
    #pragma unroll
    for (int d = 0; d < 8; ++d) wxr[d] = w0g[c * 32 + d * 2 + tap];
    // rotation-ordered weights: W[r] pairs with value of channel ((l15+dir*r)&15)+hbase
    float w1n[16], w1o[16], w2n[16], w2o[16], w3n[16], w3o[16];
    #pragma unroll
    for (int r = 0; r < 16; ++r) {
        int j = hbase + ((l15 + dir * r) & 15);
        w1n[r] = w1g[c * 64 + j * 2 + 1];
        w1o[r] = w1g[c * 64 + j * 2 + 0];
        w2n[r] = w2g[c * 64 + j * 2 + 1];
        w2o[r] = w2g[c * 64 + j * 2 + 0];
        w3n[r] = w3g[o3 * 64 + j * 2 + 1];
        w3o[r] = w3g[o3 * 64 + j * 2 + 0];
    }
    const float b0r  = b0g[c];
    const float b1r  = b1g[c];
    const float b2r  = b2g[c];
    const float b3r  = b3g[o3];
    const float tinv = frcp(tempg[0]);
    const float klog = tinv * INVLN2f;     // a3 coefficient in exp2 domain

    // ---- prologue: x columns ----
    if (lane < 15) {
        #pragma unroll
        for (int d = 0; d < ND; ++d) xcol[lane][d] = 0.f;
    }
    const float* xb = xg + b * (ND * TLEN);
    for (int t = lane; t < TLEN; t += 64) {
        #pragma unroll
        for (int d = 0; d < ND; ++d) xcol[15 + t][d] = xb[d * TLEN + t];
    }
    // ---- prologue: Gumbel noise, pre-scaled: g2 = g * tinv / ln2 ----
    for (int idx = lane; idx < NSTEPS * NK; idx += 64) {
        int s = idx >> 3, k = idx & 7;
        float uu = ug[s * (NB * NK) + b * NK + k];
        float g  = -flog(-flog(uu + 1e-10f) + 1e-10f);
        gls[idx] = g * klog;
    }
    // ---- z_all[:, :, 0:16] = 0 ----
    const int zoff = b * (NK * TLEN);
    const int qoff = NB * NK * TLEN + b * (NK * NSTEPS);
    for (int idx = lane; idx < NK * 16; idx += 64) {
        outg[zoff + (idx >> 4) * TLEN + (idx & 15)] = 0.f;
    }
    __syncthreads();   // xcol/gls written by all lanes before use (single wave: cheap)

    // ---- state ----
    float zA[8], zB[8];
    #pragma unroll
    for (int k = 0; k < 8; ++k) { zA[k] = 0.f; zB[k] = 0.f; }
    float RA = 1.f, RB = 1.f;              // 1/sum for each z buffer
    float P1[2] = { b1r, b1r };
    float P2[4] = { b2r, b2r, b2r, b2r };
    float P3[8];
    #pragma unroll
    for (int k = 0; k < 8; ++k) P3[k] = b3r;
    float ZQ2 = 0.f, ZQ2n = 0.f;
    float XZ;
    {
        const float4* xq = (const float4*)&xcol[tap][0];
        float4 xa = xq[0], xbv = xq[1];
        float s0 = fmaf(wxr[0], xa.x, fmaf(wxr[1], xa.y, 0.f));
        float s1 = fmaf(wxr[2], xa.z, fmaf(wxr[3], xa.w, 0.f));
        float s2 = fmaf(wxr[4], xbv.x, fmaf(wxr[5], xbv.y, 0.f));
        float s3 = fmaf(wxr[6], xbv.z, fmaf(wxr[7], xbv.w, 0.f));
        XZ = xhalfsum((s0 + s1) + (s2 + s3)) + b0r;   // old-tap z = 0
    }

    // ---- warmup q=1..14 ----
    #pragma unroll
    for (int q = 1; q <= 14; ++q) STEP(q, q & 1, q & 3, q & 7, zA, zB, RA, RB, 0);

    // ---- main loop q=15..510, unrolled by 8; z double-buffer by parity ----
    for (int qb = 15; qb <= 503; qb += 8) {
        #pragma unroll
        for (int u = 0; u < 8; u += 2) {
            STEP(qb + u,     (15 + u) & 1, (15 + u) & 3, (15 + u) & 7, zA, zB, RA, RB, 1);
            STEP(qb + u + 1, (16 + u) & 1, (16 + u) & 3, (16 + u) & 7, zB, zA, RB, RA, 1);
        }
    }
}

extern "C" void kernel_launch(void* const* d_in, const int* in_sizes, int n_in,
                              void* d_out, int out_size, void* d_ws, size_t ws_size,
                              hipStream_t stream) {
    (void)in_sizes; (void)n_in; (void)out_size; (void)d_ws; (void)ws_size;
    regime_scan_kernel<<<dim3(NB), dim3(64), 0, stream>>>(
        (const float*)d_in[0],   // x
        (const float*)d_in[1],   // temp
        (const float*)d_in[2],   // u
        (const float*)d_in[3],   // w0
        (const float*)d_in[4],   // b0
        (const float*)d_in[5],   // w1
        (const float*)d_in[6],   // b1
        (const float*)d_in[7],   // w2
        (const float*)d_in[8],   // b2
        (const float*)d_in[9],   // w3
        (const float*)d_in[10],  // b3
        (float*)d_out);
}

// Round 14
// 356.598 us; speedup vs baseline: 1.0943x; 1.0943x over previous
//
#include <hip/hip_runtime.h>

// Problem constants (from reference)
#define NB      128
#define ND      8
#define NK      8
#define TLEN    512
#define NSTEPS  496

#define INVLN2f 1.44269504088896340736f

__device__ __forceinline__ float fexp(float x) { return __expf(x); }
__device__ __forceinline__ float flog(float x) { return __logf(x); }
__device__ __forceinline__ float frcp(float x) { return __builtin_amdgcn_rcpf(x); }
__device__ __forceinline__ float elur(float x) { return x > 0.f ? x : fexp(x) - 1.f; }

#if defined(__has_builtin)
#if __has_builtin(__builtin_amdgcn_exp2f)
#define fexp2(x) __builtin_amdgcn_exp2f(x)
#endif
#endif
#ifndef fexp2
#define fexp2(x) exp2f(x)
#endif

// DPP helpers. Data replicated every 8 lanes => within a 16-lane row:
// quad_perm 0xB1 = lane^1, 0x4E = lane^2, row_ror:4 acts as lane^4.
#define DPP_ROR4(v) __int_as_float(__builtin_amdgcn_mov_dpp(__float_as_int(v), 0x124, 0xF, 0xF, false))
#define DPP_X1(v)   __int_as_float(__builtin_amdgcn_mov_dpp(__float_as_int(v), 0xB1, 0xF, 0xF, false))
#define DPP_X2(v)   __int_as_float(__builtin_amdgcn_mov_dpp(__float_as_int(v), 0x4E, 0xF, 0xF, false))
#define DPP_RORN(v, ctrl) __int_as_float(__builtin_amdgcn_mov_dpp(__float_as_int(v), (ctrl), 0xF, 0xF, false))

#define RED8_MAX(m) { m = fmaxf(m, DPP_X1(m)); m = fmaxf(m, DPP_X2(m)); m = fmaxf(m, DPP_ROR4(m)); }
#define RED8_SUM(s) { s = s + DPP_X1(s); s = s + DPP_X2(s); s = s + DPP_ROR4(s); }

// v + v[lane^32] on all lanes, via VALU permlane32_swap (no DS pipe).
#if defined(__has_builtin)
#if __has_builtin(__builtin_amdgcn_permlane32_swap)
#define HAVE_PLSWAP 1
#endif
#endif
#ifdef HAVE_PLSWAP
typedef unsigned int uint2v __attribute__((ext_vector_type(2)));
__device__ __forceinline__ float xhalfsum(float v) {
    unsigned int u = __float_as_uint(v);
    uint2v r = __builtin_amdgcn_permlane32_swap(u, u, false, false);
    return __uint_as_float(r[0]) + __uint_as_float(r[1]);
}
#else
__device__ __forceinline__ float xhalfsum(float v) { return v + __shfl_xor(v, 32); }
#endif

// dual 16-term dot (new+old tap weights) over 16 floats of LDS (4x b128 reads,
// both dots reuse the same loaded registers — do NOT split, compiler won't CSE)
__device__ __forceinline__ void ldot16x2(const float* p, const float* wn, const float* wo,
                                         float& dn, float& dd) {
    const float4* q4 = (const float4*)p;
    float n0 = 0.f, n1 = 0.f, o0 = 0.f, o1 = 0.f;
    #pragma unroll
    for (int i = 0; i < 4; ++i) {
        float4 v = q4[i];
        n0 = fmaf(wn[4*i+0], v.x, n0);
        n1 = fmaf(wn[4*i+1], v.y, n1);
        o0 = fmaf(wo[4*i+0], v.x, o0);
        o1 = fmaf(wo[4*i+1], v.y, o1);
        n0 = fmaf(wn[4*i+2], v.z, n0);
        n1 = fmaf(wn[4*i+3], v.w, n1);
        o0 = fmaf(wo[4*i+2], v.z, o0);
        o1 = fmaf(wo[4*i+3], v.w, o1);
    }
    dn = n0 + n1;
    dd = o0 + o1;
}

// One scan step. z-feedback is fully pipelined into XZ: at step q's DO_OUT we
// rotate F(q) across the 8-lane group (row_ror DPP), dot with rotation-ordered
// wzn/wzo, scale by r2, and park: ZN (consumed at q+1 via XZ) and ZQ2n
// (consumed at q+2). L0 on the critical path is just elur(XZ).
// gls holds g2 = g*tinv/ln2; F = 2^(a3*klog + g2), max-sub skipped (bounded).
#define STEP(qv, S1, S2, S3, DO_OUT)                                              \
  {                                                                               \
    const int q_ = (qv);                                                          \
    float g2_own = 0.f;                                                           \
    if (DO_OUT) g2_own = gls[(q_ - 15) * NK + o3];                                \
    const float4* _xq = (const float4*)&xcol[q_ + tap][0];                        \
    float4 _xa = _xq[0], _xb = _xq[1];                                            \
    /* layer 0: all contributions pre-folded into XZ */                           \
    float o0v = elur(XZ);                                                         \
    bc0[lane] = o0v;                                                              \
    /* layer 1 */                                                                 \
    float n1, d1o;                                                                \
    ldot16x2(bc0 + hoff, w1n, w1o, n1, d1o);                                      \
    float o1v = elur(xhalfsum(n1) + P1[S1]);                                      \
    bc1[lane] = o1v;                                                              \
    P1[S1] = b1r + xhalfsum(d1o);                                                 \
    /* layer 2 */                                                                 \
    float n2, d2o;                                                                \
    ldot16x2(bc1 + hoff, w2n, w2o, n2, d2o);                                      \
    float o2v = elur(xhalfsum(n2) + P2[S2]);                                      \
    bc2[lane] = o2v;                                                              \
    P2[S2] = b2r + xhalfsum(d2o);                                                 \
    /* layer 3 */                                                                 \
    float n3, d3o;                                                                \
    ldot16x2(bc2 + hoff, w3n, w3o, n3, d3o);                                      \
    float a3m = elur(xhalfsum(n3) + P3[S3]);                                      \
    P3[S3] = b3r + xhalfsum(d3o);                                                 \
    if (DO_OUT) {                                                                 \
      /* feedback gumbel-softmax: single exp2, no max-sub */                      \
      float F = fexp2(fmaf(a3m, klog, g2_own));                                   \
      float S = F; RED8_SUM(S);                                                   \
      float r2 = frcp(S);                                                         \
      /* rotate F across the 8-group; dot with rotation-ordered z-weights */      \
      float rt1 = DPP_RORN(F, 0x121), rt2 = DPP_RORN(F, 0x122);                   \
      float rt3 = DPP_RORN(F, 0x123), rt4 = DPP_RORN(F, 0x124);                   \
      float rt5 = DPP_RORN(F, 0x125), rt6 = DPP_RORN(F, 0x126);                   \
      float rt7 = DPP_RORN(F, 0x127);                                             \
      float na = wznrot[0] * F,   nb = wznrot[1] * rt1;                           \
      float nc = wznrot[2] * rt2, nd = wznrot[3] * rt3;                           \
      na = fmaf(wznrot[4], rt4, na); nb = fmaf(wznrot[5], rt5, nb);               \
      nc = fmaf(wznrot[6], rt6, nc); nd = fmaf(wznrot[7], rt7, nd);               \
      float oa = wzorot[0] * F,   ob = wzorot[1] * rt1;                           \
      float oc = wzorot[2] * rt2, od = wzorot[3] * rt3;                           \
      oa = fmaf(wzorot[4], rt4, oa); ob = fmaf(wzorot[5], rt5, ob);               \
      oc = fmaf(wzorot[6], rt6, oc); od = fmaf(wzorot[7], rt7, od);               \
      ZN   = ((na + nb) + (nc + nd)) * r2;   /* wzn.y(q) -> XZ at q+1 */          \
      ZQ2n = ((oa + ob) + (oc + od)) * r2;   /* wzo.y(q) -> XZ at q+2 */          \
      /* off-path: log-softmax output */                                          \
      float mx = a3m; RED8_MAX(mx);                                               \
      float e = fexp(a3m - mx);                                                   \
      float se = e; RED8_SUM(se);                                                 \
      float lse = mx + flog(se);                                                  \
      if (lane < 8) {                                                             \
        outg[zoff + lane * TLEN + q_ + 1]       = F * r2;                         \
        outg[qoff + lane * NSTEPS + (q_ - 15)]  = a3m - lse;                      \
      }                                                                           \
    }                                                                             \
    /* park x-part + z-feedback for step q_+1: ZQ2 == wzo.y(q_-1) here */         \
    {                                                                             \
      float s0 = fmaf(wxr[0], _xa.x, fmaf(wxr[1], _xa.y, 0.f));                   \
      float s1 = fmaf(wxr[2], _xa.z, fmaf(wxr[3], _xa.w, 0.f));                   \
      float s2 = fmaf(wxr[4], _xb.x, fmaf(wxr[5], _xb.y, 0.f));                   \
      float s3 = fmaf(wxr[6], _xb.z, fmaf(wxr[7], _xb.w, 0.f));                   \
      float xp = (s0 + s1) + (s2 + s3);                                           \
      XZ = (xhalfsum(xp) + b0r + ZQ2) + ZN;                                       \
      ZQ2 = ZQ2n;                                                                 \
    }                                                                             \
  }

__global__ __launch_bounds__(64, 1)
void regime_scan_kernel(const float* __restrict__ xg,
                        const float* __restrict__ tempg,
                        const float* __restrict__ ug,
                        const float* __restrict__ w0g,
                        const float* __restrict__ b0g,
                        const float* __restrict__ w1g,
                        const float* __restrict__ b1g,
                        const float* __restrict__ w2g,
                        const float* __restrict__ b2g,
                        const float* __restrict__ w3g,
                        const float* __restrict__ b3g,
                        float* __restrict__ outg)
{
    __shared__ __align__(16) float xcol[527][8];     // 16.9 KB
    __shared__ __align__(16) float gls[NSTEPS * NK]; // 15.9 KB (holds g2)
    __shared__ __align__(16) float bc0[64], bc1[64], bc2[64];

    const int lane = threadIdx.x;
    const int b    = blockIdx.x;
    const int c    = lane & 31;            // channel owned
    const int o3   = lane & 7;             // layer-3 channel owned
    const int half = lane >> 5;            // K-half owned (layers 1-3)
    const int hoff = half << 4;            // float offset into bc
    const int tap  = (lane < 32) ? 1 : 0;  // x-park tap role

    // ---- runtime probe (uniform): row_ror direction on this HW ----
    int dir;
    {
        int l15 = lane & 15;
        int rr1 = __builtin_amdgcn_mov_dpp(l15, 0x121, 0xF, 0xF, false); // row_ror:1
        dir = (rr1 == ((l15 + 1) & 15)) ? 1 : -1;
    }

    // ---- per-lane weights ----
    // layer0 z weights in ROTATION order: slot r pairs with F-channel (o3+dir*r)&7
    float wznrot[8], wzorot[8];
    #pragma unroll
    for (int r = 0; r < 8; ++r) {
        int ch = (o3 + dir * r) & 7;
        wznrot[r] = w0g[c * 32 + (8 + ch) * 2 + 1];
        wzorot[r] = w0g[c * 32 + (8 + ch) * 2 + 0];
    }
    float wxr[8];
    #pragma unroll
    for (int d = 0; d < 8; ++d) wxr[d] = w0g[c * 32 + d * 2 + tap];
    float w1n[16], w1o[16], w2n[16], w2o[16], w3n[16], w3o[16];
    #pragma unroll
    for (int i = 0; i < 16; ++i) {
        int j = hoff + i;
        w1n[i] = w1g[c * 64 + j * 2 + 1];
        w1o[i] = w1g[c * 64 + j * 2 + 0];
        w2n[i] = w2g[c * 64 + j * 2 + 1];
        w2o[i] = w2g[c * 64 + j * 2 + 0];
        w3n[i] = w3g[o3 * 64 + j * 2 + 1];
        w3o[i] = w3g[o3 * 64 + j * 2 + 0];
    }
    const float b0r  = b0g[c];
    const float b1r  = b1g[c];
    const float b2r  = b2g[c];
    const float b3r  = b3g[o3];
    const float tinv = frcp(tempg[0]);
    const float klog = tinv * INVLN2f;     // a3 coefficient in exp2 domain

    // ---- prologue: x columns ----
    if (lane < 15) {
        #pragma unroll
        for (int d = 0; d < ND; ++d) xcol[lane][d] = 0.f;
    }
    const float* xb = xg + b * (ND * TLEN);
    for (int t = lane; t < TLEN; t += 64) {
        #pragma unroll
        for (int d = 0; d < ND; ++d) xcol[15 + t][d] = xb[d * TLEN + t];
    }
    // ---- prologue: Gumbel noise, pre-scaled: g2 = g * tinv / ln2 ----
    for (int idx = lane; idx < NSTEPS * NK; idx += 64) {
        int s = idx >> 3, k = idx & 7;
        float uu = ug[s * (NB * NK) + b * NK + k];
        float g  = -flog(-flog(uu + 1e-10f) + 1e-10f);
        gls[idx] = g * klog;
    }
    // ---- z_all[:, :, 0:16] = 0 ----
    const int zoff = b * (NK * TLEN);
    const int qoff = NB * NK * TLEN + b * (NK * NSTEPS);
    for (int idx = lane; idx < NK * 16; idx += 64) {
        outg[zoff + (idx >> 4) * TLEN + (idx & 15)] = 0.f;
    }

    // ---- state ----
    float P1[2] = { b1r, b1r };
    float P2[4] = { b2r, b2r, b2r, b2r };
    float P3[8];
    #pragma unroll
    for (int k = 0; k < 8; ++k) P3[k] = b3r;
    float ZQ2 = 0.f, ZQ2n = 0.f, ZN = 0.f;
    float XZ;
    {
        const float4* xq = (const float4*)&xcol[tap][0];
        float4 xa = xq[0], xbv = xq[1];
        float s0 = fmaf(wxr[0], xa.x, fmaf(wxr[1], xa.y, 0.f));
        float s1 = fmaf(wxr[2], xa.z, fmaf(wxr[3], xa.w, 0.f));
        float s2 = fmaf(wxr[4], xbv.x, fmaf(wxr[5], xbv.y, 0.f));
        float s3 = fmaf(wxr[6], xbv.z, fmaf(wxr[7], xbv.w, 0.f));
        XZ = xhalfsum((s0 + s1) + (s2 + s3)) + b0r;   // z = 0 at start
    }

    // ---- warmup q=1..14 (z stays zero; ZN/ZQ2 remain 0) ----
    #pragma unroll
    for (int q = 1; q <= 14; ++q) STEP(q, q & 1, q & 3, q & 7, 0);

    // ---- main loop q=15..510, unrolled by 8 ----
    for (int qb = 15; qb <= 503; qb += 8) {
        #pragma unroll
        for (int u = 0; u < 8; ++u) {
            STEP(qb + u, (15 + u) & 1, (15 + u) & 3, (15 + u) & 7, 1);
        }
    }
}

extern "C" void kernel_launch(void* const* d_in, const int* in_sizes, int n_in,
                              void* d_out, int out_size, void* d_ws, size_t ws_size,
                              hipStream_t stream) {
    (void)in_sizes; (void)n_in; (void)out_size; (void)d_ws; (void)ws_size;
    regime_scan_kernel<<<dim3(NB), dim3(64), 0, stream>>>(
        (const float*)d_in[0],   // x
        (const float*)d_in[1],   // temp
        (const float*)d_in[2],   // u
        (const float*)d_in[3],   // w0
        (const float*)d_in[4],   // b0
        (const float*)d_in[5],   // w1
        (const float*)d_in[6],   // b1
        (const float*)d_in[7],   // w2
        (const float*)d_in[8],   // b2
        (const float*)d_in[9],   // w3
        (const float*)d_in[10],  // b3
        (float*)d_out);
}